// Round 2
// baseline (321.952 us; speedup 1.0000x reference)
//
#include <hip/hip_runtime.h>
#include <math.h>

// Problem constants (fixed by setup_inputs): B=16, T=4096, D=512, fp32.
#define BB 16
#define TT 4096
#define DD 512
#define D4 128   // DD / 4 (float4 columns)
#define CC 128   // time chunks
#define LL 32    // TT / CC
#define NBY 8    // BB / 2 row-pair groups

// ws layout (bytes): [0..4) ticket counter | [256..256+4*NBY*CC) flags | [8192..) ends
#define FLAGS_OFF_U32 64   // flags start at uint index 64 (byte 256)
#define ENDS_OFF_B    8192

typedef float v4f __attribute__((ext_vector_type(4)));

__device__ __forceinline__ float sigmf(float v) {
    return 1.0f / (1.0f + expf(-v));
}

// Nontemporal float4 store: out is write-once/never-read; keep it from
// evicting x out of the 256 MB Infinity Cache.
__device__ __forceinline__ void nt_store4(float4* p, const float4& s) {
    __builtin_nontemporal_store(*reinterpret_cast<const v4f*>(&s),
                                reinterpret_cast<v4f*>(p));
}

// Single-pass chained scan with decoupled lookback.
// Grid: CC*NBY blocks, 256 threads (2 b-rows x 128 float4 cols).
// Ticket -> (by, c) so chunk order == start order: a block only ever waits on
// blocks with smaller tickets (already running or finished) -> no deadlock
// regardless of HW dispatch order.
__global__ __launch_bounds__(256) void es_single(
    const float* __restrict__ x, const float* __restrict__ alpha,
    unsigned int* __restrict__ hdr, float* __restrict__ out)
{
    const int tid = threadIdx.x;

    __shared__ unsigned int tkt_s;
    if (tid == 0) tkt_s = atomicAdd(hdr, 1u);   // device-scope (m20)
    __syncthreads();
    const unsigned int t = tkt_s;
    const int by = (int)(t & (NBY - 1));
    const int c  = (int)(t >> 3);

    const int b  = (by << 1) + (tid >> 7);
    const int d4 = tid & 127;

    unsigned int* flags = hdr + FLAGS_OFF_U32;
    float4* ends = reinterpret_cast<float4*>(reinterpret_cast<char*>(hdr) + ENDS_OFF_B);

    const float4 al = reinterpret_cast<const float4*>(alpha)[d4];
    const float ax = sigmf(al.x), ay = sigmf(al.y), az = sigmf(al.z), aw = sigmf(al.w);
    const float fx = 1.0f - ax, fy = 1.0f - ay, fz = 1.0f - az, fw = 1.0f - aw;

    const size_t base = ((size_t)b * TT + (size_t)c * LL) * D4 + d4;
    const float4* xp = reinterpret_cast<const float4*>(x) + base;
    float4*       op = reinterpret_cast<float4*>(out) + base;

    // ---- Phase 1: load whole chunk into registers (32 INDEPENDENT loads,
    // all issued back-to-back -> ~32 loads in flight per wave vs ~8 before).
    float4 buf[LL];
    #pragma unroll
    for (int i = 0; i < LL; ++i) buf[i] = xp[(size_t)i * D4];

    // ---- Phase 2: zero-init local scan -> chunk end E_c.
    // (c==0: virtual s_{-1} = x_0 -> E_0 exact.) Same FMA order as before.
    float4 s;
    if (c == 0) { s = buf[0]; }
    else        { s.x = s.y = s.z = s.w = 0.0f; }
    #pragma unroll
    for (int i = 0; i < LL; ++i) {
        s.x = fmaf(ax, buf[i].x, fx * s.x);
        s.y = fmaf(ay, buf[i].y, fy * s.y);
        s.z = fmaf(az, buf[i].z, fz * s.z);
        s.w = fmaf(aw, buf[i].w, fw * s.w);
    }
    ends[((size_t)b * CC + c) * D4 + d4] = s;

    // __syncthreads drains vmcnt(0): all 256 threads' E stores have reached L2
    // before thread 0 publishes. Agent-scope release writes back L2 so the E
    // lines reach the coherent point before the flag does.
    __syncthreads();
    if (tid == 0) {
        __hip_atomic_store(&flags[(by << 7) + c], 1u,
                           __ATOMIC_RELEASE, __HIP_MEMORY_SCOPE_AGENT);
    }

    // ---- Phase 3: decoupled lookback. Lane tid spins on flag[tid] (tid < c):
    // one vectorized relaxed agent load polls up to 64 flags per wave.
    float4 S;
    if (c > 0) {
        if (tid < c) {
            while (__hip_atomic_load(&flags[(by << 7) + tid],
                                     __ATOMIC_RELAXED, __HIP_MEMORY_SCOPE_AGENT) == 0u) {
                __builtin_amdgcn_s_sleep(2);
            }
        }
        __syncthreads();
        __builtin_amdgcn_fence(__ATOMIC_ACQUIRE, "agent");  // one invalidate, then plain reads

        float4 fL;
        fL.x = powf(fx, (float)LL);
        fL.y = powf(fy, (float)LL);
        fL.z = powf(fz, (float)LL);
        fL.w = powf(fw, (float)LL);

        const float4* e = ends + (size_t)b * CC * D4 + d4;
        S = e[0];                        // S_0 = E_0 (exact)
        int j = 1;
        for (; j + 4 <= c; j += 4) {     // mild prefetch; FMA order unchanged
            float4 v0 = e[(size_t)(j + 0) * D4];
            float4 v1 = e[(size_t)(j + 1) * D4];
            float4 v2 = e[(size_t)(j + 2) * D4];
            float4 v3 = e[(size_t)(j + 3) * D4];
            S.x = fmaf(fL.x, S.x, v0.x); S.y = fmaf(fL.y, S.y, v0.y);
            S.z = fmaf(fL.z, S.z, v0.z); S.w = fmaf(fL.w, S.w, v0.w);
            S.x = fmaf(fL.x, S.x, v1.x); S.y = fmaf(fL.y, S.y, v1.y);
            S.z = fmaf(fL.z, S.z, v1.z); S.w = fmaf(fL.w, S.w, v1.w);
            S.x = fmaf(fL.x, S.x, v2.x); S.y = fmaf(fL.y, S.y, v2.y);
            S.z = fmaf(fL.z, S.z, v2.z); S.w = fmaf(fL.w, S.w, v2.w);
            S.x = fmaf(fL.x, S.x, v3.x); S.y = fmaf(fL.y, S.y, v3.y);
            S.z = fmaf(fL.z, S.z, v3.z); S.w = fmaf(fL.w, S.w, v3.w);
        }
        for (; j < c; ++j) {
            const float4 v = e[(size_t)j * D4];
            S.x = fmaf(fL.x, S.x, v.x);
            S.y = fmaf(fL.y, S.y, v.y);
            S.z = fmaf(fL.z, S.z, v.z);
            S.w = fmaf(fL.w, S.w, v.w);
        }
    }

    // ---- Phase 4: final scan from the exact carry, entirely from registers
    // (x never re-read). Same FMA order as the old K3 -> bit-identical output.
    float4 sf;
    if (c == 0) sf = buf[0];
    else        sf = S;
    #pragma unroll
    for (int i = 0; i < LL; ++i) {
        sf.x = fmaf(ax, buf[i].x, fx * sf.x);
        sf.y = fmaf(ay, buf[i].y, fy * sf.y);
        sf.z = fmaf(az, buf[i].z, fz * sf.z);
        sf.w = fmaf(aw, buf[i].w, fw * sf.w);
        nt_store4(op + (size_t)i * D4, sf);
    }
}

// Fallback: full serial scan per (b, d4) column if ws is too small.
__global__ __launch_bounds__(256) void es_serial(
    const float* __restrict__ x, const float* __restrict__ alpha,
    float* __restrict__ out)
{
    const int g  = blockIdx.x * 256 + threadIdx.x;   // 0..2047
    const int b  = g >> 7;
    const int d4 = g & 127;

    const float4 al = reinterpret_cast<const float4*>(alpha)[d4];
    const float ax = sigmf(al.x), ay = sigmf(al.y), az = sigmf(al.z), aw = sigmf(al.w);
    const float fx = 1.0f - ax, fy = 1.0f - ay, fz = 1.0f - az, fw = 1.0f - aw;

    const float4* xp = reinterpret_cast<const float4*>(x) + (size_t)b * TT * D4 + d4;
    float4*       op = reinterpret_cast<float4*>(out) + (size_t)b * TT * D4 + d4;

    float4 s = xp[0];
    #pragma unroll 4
    for (int t = 0; t < TT; ++t) {
        const float4 v = xp[(size_t)t * D4];
        s.x = fmaf(ax, v.x, fx * s.x);
        s.y = fmaf(ay, v.y, fy * s.y);
        s.z = fmaf(az, v.z, fz * s.z);
        s.w = fmaf(aw, v.w, fw * s.w);
        op[(size_t)t * D4] = s;
    }
}

extern "C" void kernel_launch(void* const* d_in, const int* in_sizes, int n_in,
                              void* d_out, int out_size, void* d_ws, size_t ws_size,
                              hipStream_t stream)
{
    const float* x     = (const float*)d_in[0];
    const float* alpha = (const float*)d_in[1];
    float*       out   = (float*)d_out;

    const size_t need = (size_t)ENDS_OFF_B + (size_t)BB * CC * DD * sizeof(float);
    if (ws_size < need) {
        // Workspace too small for chunking: serial fallback (correct, slower).
        es_serial<<<dim3(8), 256, 0, stream>>>(x, alpha, out);
        return;
    }

    // Zero ticket counter + flags (8 KB). Graph-capturable async op.
    hipMemsetAsync(d_ws, 0, ENDS_OFF_B, stream);

    es_single<<<dim3(CC * NBY), 256, 0, stream>>>(
        x, alpha, (unsigned int*)d_ws, out);
}